// Round 6
// baseline (167.061 us; speedup 1.0000x reference)
//
#include <hip/hip_runtime.h>
#include <math.h>

#define Hdim 64
#define Wdim 64
#define NTOK 8192

typedef unsigned short ushortT;
typedef __attribute__((ext_vector_type(8))) short short8;
typedef __attribute__((ext_vector_type(4))) float floatx4;

__device__ inline ushortT f2bf(float x) {
    union { float f; unsigned u; } v; v.f = x;
    unsigned r = (v.u + 0x7fffu + ((v.u >> 16) & 1u)) >> 16;
    return (ushortT)r;
}

#define GLOAD_LDS16(g, l) __builtin_amdgcn_global_load_lds( \
    (const __attribute__((address_space(1))) unsigned int*)(g), \
    (__attribute__((address_space(3))) unsigned int*)(l), 16, 0, 0)

// ---------------- prep: weight fp32->bf16 (blocks 0..767) + LN1 (768..2815) --
__global__ __launch_bounds__(256) void prep_kernel(
        const float* __restrict__ qkv_w, const float* __restrict__ proj_w,
        const float* __restrict__ fc1_w, const float* __restrict__ fc2_w,
        ushortT* __restrict__ o_qkv, ushortT* __restrict__ o_proj,
        ushortT* __restrict__ o_fc1, ushortT* __restrict__ o_fc2,
        const float* __restrict__ x, const float* __restrict__ ln1_w,
        const float* __restrict__ ln1_b, ushortT* __restrict__ xn) {
    if (blockIdx.x < 768) {
        int idx = blockIdx.x * 256 + threadIdx.x;  // one float4 per thread
        const float* src; ushortT* dst; int local;
        if (idx < 49152)        { src = qkv_w;  dst = o_qkv;  local = idx; }
        else if (idx < 65536)   { src = proj_w; dst = o_proj; local = idx - 49152; }
        else if (idx < 131072)  { src = fc1_w;  dst = o_fc1;  local = idx - 65536; }
        else                    { src = fc2_w;  dst = o_fc2;  local = idx - 131072; }
        float4 v = ((const float4*)src)[local];
        ushortT o[4] = {f2bf(v.x), f2bf(v.y), f2bf(v.z), f2bf(v.w)};
        *(uint2*)(dst + (size_t)local * 4) = *(uint2*)o;
    } else {
        int wave = threadIdx.x >> 6, lane = threadIdx.x & 63;
        int t = (blockIdx.x - 768) * 4 + wave;
        float4 v = *(const float4*)(x + (size_t)t * 256 + lane * 4);
        float s = v.x + v.y + v.z + v.w;
        float sq = v.x * v.x + v.y * v.y + v.z * v.z + v.w * v.w;
#pragma unroll
        for (int off = 32; off > 0; off >>= 1) {
            s  += __shfl_xor(s, off, 64);
            sq += __shfl_xor(sq, off, 64);
        }
        float mean = s * (1.0f / 256.0f);
        float var  = sq * (1.0f / 256.0f) - mean * mean;
        float r = rsqrtf(var + 1e-5f);
        float4 wv = *(const float4*)(ln1_w + lane * 4);
        float4 bv = *(const float4*)(ln1_b + lane * 4);
        ushortT o[4] = {f2bf((v.x - mean) * r * wv.x + bv.x),
                        f2bf((v.y - mean) * r * wv.y + bv.y),
                        f2bf((v.z - mean) * r * wv.z + bv.z),
                        f2bf((v.w - mean) * r * wv.w + bv.w)};
        *(uint2*)(xn + (size_t)t * 256 + lane * 4) = *(uint2*)o;
    }
}

// ---------------- LayerNorm v2: one wave per token -------------------------
__global__ __launch_bounds__(256) void ln_v2(const float* __restrict__ x,
                                             const float* __restrict__ w,
                                             const float* __restrict__ b,
                                             ushortT* __restrict__ y) {
    int wave = threadIdx.x >> 6, lane = threadIdx.x & 63;
    int t = blockIdx.x * 4 + wave;
    float4 v = *(const float4*)(x + (size_t)t * 256 + lane * 4);
    float s = v.x + v.y + v.z + v.w;
    float sq = v.x * v.x + v.y * v.y + v.z * v.z + v.w * v.w;
#pragma unroll
    for (int off = 32; off > 0; off >>= 1) {
        s  += __shfl_xor(s, off, 64);
        sq += __shfl_xor(sq, off, 64);
    }
    float mean = s * (1.0f / 256.0f);
    float var  = sq * (1.0f / 256.0f) - mean * mean;
    float r = rsqrtf(var + 1e-5f);
    float4 wv = *(const float4*)(w + lane * 4);
    float4 bv = *(const float4*)(b + lane * 4);
    ushortT o[4] = {f2bf((v.x - mean) * r * wv.x + bv.x),
                    f2bf((v.y - mean) * r * wv.y + bv.y),
                    f2bf((v.z - mean) * r * wv.z + bv.z),
                    f2bf((v.w - mean) * r * wv.w + bv.w)};
    *(uint2*)(y + (size_t)t * 256 + lane * 4) = *(uint2*)o;
}

// ---------------- bf16 MFMA GEMM v3 (m97-style): C = A @ Bw^T + bias ---------
// 128x128 block tile, BK=64, 256 threads = 4 waves (2x2), each wave 64x64 (4x4 acc).
// LDS rows of 64 ushort (128B = 8 chunks); chunk c of row r stored at pos c^(r&7).
// Staging: 4+4 global_load_lds width-16 rounds per k-iter (wave-uniform bases).
// EPI: 0 = qkv split-heads bf16 (q pre-scaled), 1 = bias + fp32 residual -> fp32,
//      2 = bias + exact GELU -> bf16
template <int EPI>
__global__ __launch_bounds__(256) void gemm_bf16_v3(const ushortT* __restrict__ A,
                                                    const ushortT* __restrict__ Bw,
                                                    const float* __restrict__ bias,
                                                    const float* __restrict__ res,
                                                    void* __restrict__ out0,
                                                    ushortT* __restrict__ kb,
                                                    ushortT* __restrict__ vb,
                                                    int N, int K) {
    __shared__ ushortT As[128 * 64];  // 16KB
    __shared__ ushortT Bs[128 * 64];  // 16KB
    const int tid  = threadIdx.x;
    const int wave = tid >> 6, lane = tid & 63;
    const int wm = wave >> 1, wn = wave & 1;
    const int ln16 = lane & 15, kg = lane >> 4;
    const int m0 = blockIdx.y * 128, n0 = blockIdx.x * 128;

    // staging map: id = q*256 + tid; LDS slot (row=id>>3, pos=id&7) <- global chunk pos^(row&7)
    const int srow = tid >> 3;          // row for q=0; +32 per round
    const int spos = tid & 7;
    const int sgc  = spos ^ (srow & 7); // global chunk (row&7 invariant under +32)

    const floatx4 fzero = {0.f, 0.f, 0.f, 0.f};
    floatx4 acc[4][4];
#pragma unroll
    for (int i = 0; i < 4; ++i)
#pragma unroll
        for (int j = 0; j < 4; ++j) acc[i][j] = fzero;

    for (int kt = 0; kt < K; kt += 64) {
#pragma unroll
        for (int q = 0; q < 4; ++q) {
            int row = q * 32 + srow;
            GLOAD_LDS16(A  + (size_t)(m0 + row) * K + kt + sgc * 8, As + (q * 256 + tid - lane) * 8);
            GLOAD_LDS16(Bw + (size_t)(n0 + row) * K + kt + sgc * 8, Bs + (q * 256 + tid - lane) * 8);
        }
        __syncthreads();
#pragma unroll
        for (int s = 0; s < 2; ++s) {
            int c = s * 4 + kg;
            short8 a[4], b[4];
#pragma unroll
            for (int i = 0; i < 4; ++i) {
                int ra = wm * 64 + i * 16 + ln16;
                a[i] = *(const short8*)(As + ra * 64 + ((c ^ (ra & 7)) * 8));
            }
#pragma unroll
            for (int j = 0; j < 4; ++j) {
                int rb = wn * 64 + j * 16 + ln16;
                b[j] = *(const short8*)(Bs + rb * 64 + ((c ^ (rb & 7)) * 8));
            }
#pragma unroll
            for (int i = 0; i < 4; ++i)
#pragma unroll
                for (int j = 0; j < 4; ++j)
                    acc[i][j] = __builtin_amdgcn_mfma_f32_16x16x32_bf16(a[i], b[j], acc[i][j], 0, 0, 0);
        }
        __syncthreads();
    }

    // epilogue: C/D map col=ln16, row=kg*4+reg
#pragma unroll
    for (int j = 0; j < 4; ++j) {
        int col = n0 + wn * 64 + j * 16 + ln16;
        float bsv = bias[col];
        if (EPI == 0) {
            int part = col >> 8, h = (col >> 5) & 7, d = col & 31;
            ushortT* dst = part == 0 ? (ushortT*)out0 : (part == 1 ? kb : vb);
            float scl = part == 0 ? 0.17677669529663687f : 1.0f;
#pragma unroll
            for (int i = 0; i < 4; ++i)
#pragma unroll
                for (int r = 0; r < 4; ++r) {
                    int row = m0 + wm * 64 + i * 16 + kg * 4 + r;
                    int bI = row >> 12, tin = row & 4095;
                    dst[((size_t)(bI * 8 + h) * 4096 + tin) * 32 + d] =
                        f2bf((acc[i][j][r] + bsv) * scl);
                }
        } else {
#pragma unroll
            for (int i = 0; i < 4; ++i)
#pragma unroll
                for (int r = 0; r < 4; ++r) {
                    int row = m0 + wm * 64 + i * 16 + kg * 4 + r;
                    float v = acc[i][j][r] + bsv;
                    if (EPI == 1) {
                        v += res[(size_t)row * N + col];
                        ((float*)out0)[(size_t)row * N + col] = v;
                    } else {  // GELU -> bf16
                        v = 0.5f * v * (1.0f + erff(v * 0.70710678118654752f));
                        ((ushortT*)out0)[(size_t)row * N + col] = f2bf(v);
                    }
                }
        }
    }
}

// ---------------- Neighborhood attention v3 ----------------------------------
__global__ __launch_bounds__(256) void natten_v3(const ushortT* __restrict__ qb,
                                                 const ushortT* __restrict__ kb,
                                                 const ushortT* __restrict__ vb,
                                                 ushortT* __restrict__ attn_out) {
    __shared__ ushortT KVs[2 * 196 * 40];  // K rows then V rows, stride 40 (80B)
    __shared__ float Ps[64][52];
    ushortT* Ks = KVs;
    ushortT* Vs = KVs + 196 * 40;
    const int tid = threadIdx.x, bid = blockIdx.x;
    const int tile = bid & 63, h = (bid >> 6) & 7, b = bid >> 9;
    const int ti = tile >> 3, tj = tile & 7;
    const int r0 = min(max(ti * 8 - 3, 0), Hdim - 14);
    const int c0 = min(max(tj * 8 - 3, 0), Wdim - 14);
    const size_t base = (size_t)(b * 8 + h) * 4096 * 32;

    for (int idx = tid; idx < 1568; idx += 256) {
        int t = idx;
        const ushortT* src = kb;
        ushortT* dst = Ks;
        if (t >= 784) { t -= 784; src = vb; dst = Vs; }
        int pos = t >> 2, ch = t & 3;
        int dr = pos / 14, dc = pos - dr * 14;
        int tok = (r0 + dr) * 64 + (c0 + dc);
        *(uint4*)(dst + pos * 40 + ch * 8) = *(const uint4*)(src + base + (size_t)tok * 32 + ch * 8);
    }

    const int tl = tid >> 2, s = tid & 3;
    const int i = ti * 8 + (tl >> 3), j = tj * 8 + (tl & 7);
    const int si = min(max(i - 3, 0), Hdim - 7), sj = min(max(j - 3, 0), Wdim - 7);
    const int lbase = (si - r0) * 14 + (sj - c0);
    const int tin = i * 64 + j;

    float q[32];
    {
        const ushortT* qp = qb + base + (size_t)tin * 32;
#pragma unroll
        for (int c4 = 0; c4 < 4; ++c4) {
            uint4 u = *(const uint4*)(qp + c4 * 8);
            unsigned uu[4] = {u.x, u.y, u.z, u.w};
#pragma unroll
            for (int e = 0; e < 4; ++e) {
                union { unsigned v; float f; } lo, hi;
                lo.v = uu[e] << 16; hi.v = uu[e] & 0xffff0000u;
                q[c4 * 8 + e * 2] = lo.f; q[c4 * 8 + e * 2 + 1] = hi.f;
            }
        }
    }
    __syncthreads();

    float sc[13];
#pragma unroll
    for (int cI = 0; cI < 13; ++cI) {
        int n = s + cI * 4;
        if (n < 49) {
            int di = n / 7, dj = n - di * 7;
            const ushortT* kr = Ks + (lbase + di * 14 + dj) * 40;
            float a = 0.f;
#pragma unroll
            for (int c4 = 0; c4 < 4; ++c4) {
                uint4 u = *(const uint4*)(kr + c4 * 8);
                unsigned uu[4] = {u.x, u.y, u.z, u.w};
#pragma unroll
                for (int e = 0; e < 4; ++e) {
                    union { unsigned v; float f; } lo, hi;
                    lo.v = uu[e] << 16; hi.v = uu[e] & 0xffff0000u;
                    a += q[c4 * 8 + e * 2] * lo.f + q[c4 * 8 + e * 2 + 1] * hi.f;
                }
            }
            sc[cI] = a;
        }
    }
    float m = -1e30f;
#pragma unroll
    for (int cI = 0; cI < 13; ++cI) if (s + cI * 4 < 49) m = fmaxf(m, sc[cI]);
    m = fmaxf(m, __shfl_xor(m, 1, 64));
    m = fmaxf(m, __shfl_xor(m, 2, 64));
    float tot = 0.f;
#pragma unroll
    for (int cI = 0; cI < 13; ++cI) if (s + cI * 4 < 49) { sc[cI] = __expf(sc[cI] - m); tot += sc[cI]; }
    tot += __shfl_xor(tot, 1, 64);
    tot += __shfl_xor(tot, 2, 64);
    float inv = 1.0f / tot;
#pragma unroll
    for (int cI = 0; cI < 13; ++cI) if (s + cI * 4 < 49) Ps[tl][s + cI * 4] = sc[cI] * inv;
    __syncthreads();

    float o[8] = {0.f, 0.f, 0.f, 0.f, 0.f, 0.f, 0.f, 0.f};
#pragma unroll
    for (int n = 0; n < 49; ++n) {
        int di = n / 7, dj = n - di * 7;
        float p = Ps[tl][n];
        const ushortT* vr = Vs + (lbase + di * 14 + dj) * 40 + s * 8;
        uint4 u = *(const uint4*)vr;
        unsigned uu[4] = {u.x, u.y, u.z, u.w};
#pragma unroll
        for (int e = 0; e < 4; ++e) {
            union { unsigned v; float f; } lo, hi;
            lo.v = uu[e] << 16; hi.v = uu[e] & 0xffff0000u;
            o[e * 2]     += p * lo.f;
            o[e * 2 + 1] += p * hi.f;
        }
    }
    unsigned up[4];
#pragma unroll
    for (int d = 0; d < 4; ++d)
        up[d] = (unsigned)f2bf(o[2 * d]) | ((unsigned)f2bf(o[2 * d + 1]) << 16);
    size_t tq = (size_t)(b * 4096 + tin);
    *(uint4*)(attn_out + tq * 256 + h * 32 + s * 8) = make_uint4(up[0], up[1], up[2], up[3]);
}

extern "C" void kernel_launch(void* const* d_in, const int* in_sizes, int n_in,
                              void* d_out, int out_size, void* d_ws, size_t ws_size,
                              hipStream_t stream) {
    const float* x      = (const float*)d_in[0];
    const float* ln1_w  = (const float*)d_in[1];
    const float* ln1_b  = (const float*)d_in[2];
    const float* qkv_w  = (const float*)d_in[3];
    const float* qkv_b  = (const float*)d_in[4];
    const float* proj_w = (const float*)d_in[5];
    const float* proj_b = (const float*)d_in[6];
    const float* ln2_w  = (const float*)d_in[7];
    const float* ln2_b  = (const float*)d_in[8];
    const float* fc1_w  = (const float*)d_in[9];
    const float* fc1_b  = (const float*)d_in[10];
    const float* fc2_w  = (const float*)d_in[11];
    const float* fc2_b  = (const float*)d_in[12];
    float* out = (float*)d_out;

    char* ws = (char*)d_ws;
    size_t off = 0;
    ushortT* wqkv = (ushortT*)(ws + off); off += (size_t)196608 * 2;
    ushortT* wproj= (ushortT*)(ws + off); off += (size_t)65536 * 2;
    ushortT* wfc1 = (ushortT*)(ws + off); off += (size_t)262144 * 2;
    ushortT* wfc2 = (ushortT*)(ws + off); off += (size_t)262144 * 2;
    ushortT* xn   = (ushortT*)(ws + off); off += (size_t)NTOK * 256 * 2;
    ushortT* qbuf = (ushortT*)(ws + off); off += (size_t)NTOK * 256 * 2;
    ushortT* kbuf = (ushortT*)(ws + off); off += (size_t)NTOK * 256 * 2;
    ushortT* vbuf = (ushortT*)(ws + off); off += (size_t)NTOK * 256 * 2;
    ushortT* attn = (ushortT*)(ws + off); off += (size_t)NTOK * 256 * 2;
    float*   x2   = (float*)  (ws + off); off += (size_t)NTOK * 256 * 4;
    ushortT* hb   = (ushortT*)(ws + off); off += (size_t)NTOK * 256 * 2;
    ushortT* h1   = (ushortT*)(ws + off); off += (size_t)NTOK * 1024 * 2;

    dim3 blk(256);
    prep_kernel<<<2816, blk, 0, stream>>>(qkv_w, proj_w, fc1_w, fc2_w,
                                          wqkv, wproj, wfc1, wfc2,
                                          x, ln1_w, ln1_b, xn);
    gemm_bf16_v3<0><<<dim3(6, 64), blk, 0, stream>>>(xn, wqkv, qkv_b, nullptr,
                                                     qbuf, kbuf, vbuf, 768, 256);
    natten_v3<<<1024, blk, 0, stream>>>(qbuf, kbuf, vbuf, attn);
    gemm_bf16_v3<1><<<dim3(2, 64), blk, 0, stream>>>(attn, wproj, proj_b, x,
                                                     x2, nullptr, nullptr, 256, 256);
    ln_v2<<<2048, blk, 0, stream>>>(x2, ln2_w, ln2_b, hb);
    gemm_bf16_v3<2><<<dim3(8, 64), blk, 0, stream>>>(hb, wfc1, fc1_b, nullptr,
                                                     h1, nullptr, nullptr, 1024, 256);
    gemm_bf16_v3<1><<<dim3(2, 64), blk, 0, stream>>>(h1, wfc2, fc2_b, x2,
                                                     out, nullptr, nullptr, 256, 1024);
}

// Round 7
// 151.451 us; speedup vs baseline: 1.1031x; 1.1031x over previous
//
#include <hip/hip_runtime.h>
#include <math.h>

#define Hdim 64
#define Wdim 64
#define NTOK 8192

typedef unsigned short ushortT;
typedef __attribute__((ext_vector_type(8))) short short8;
typedef __attribute__((ext_vector_type(4))) float floatx4;

__device__ inline ushortT f2bf(float x) {
    union { float f; unsigned u; } v; v.f = x;
    unsigned r = (v.u + 0x7fffu + ((v.u >> 16) & 1u)) >> 16;
    return (ushortT)r;
}

#define GLOAD_LDS16(g, l) __builtin_amdgcn_global_load_lds( \
    (const __attribute__((address_space(1))) unsigned int*)(g), \
    (__attribute__((address_space(3))) unsigned int*)(l), 16, 0, 0)

// ---------------- prep: weight fp32->bf16 (blocks 0..767) + LN1 (768..2815) --
__global__ __launch_bounds__(256) void prep_kernel(
        const float* __restrict__ qkv_w, const float* __restrict__ proj_w,
        const float* __restrict__ fc1_w, const float* __restrict__ fc2_w,
        ushortT* __restrict__ o_qkv, ushortT* __restrict__ o_proj,
        ushortT* __restrict__ o_fc1, ushortT* __restrict__ o_fc2,
        const float* __restrict__ x, const float* __restrict__ ln1_w,
        const float* __restrict__ ln1_b, ushortT* __restrict__ xn) {
    if (blockIdx.x < 768) {
        int idx = blockIdx.x * 256 + threadIdx.x;  // one float4 per thread
        const float* src; ushortT* dst; int local;
        if (idx < 49152)        { src = qkv_w;  dst = o_qkv;  local = idx; }
        else if (idx < 65536)   { src = proj_w; dst = o_proj; local = idx - 49152; }
        else if (idx < 131072)  { src = fc1_w;  dst = o_fc1;  local = idx - 65536; }
        else                    { src = fc2_w;  dst = o_fc2;  local = idx - 131072; }
        float4 v = ((const float4*)src)[local];
        ushortT o[4] = {f2bf(v.x), f2bf(v.y), f2bf(v.z), f2bf(v.w)};
        *(uint2*)(dst + (size_t)local * 4) = *(uint2*)o;
    } else {
        int wave = threadIdx.x >> 6, lane = threadIdx.x & 63;
        int t = (blockIdx.x - 768) * 4 + wave;
        float4 v = *(const float4*)(x + (size_t)t * 256 + lane * 4);
        float s = v.x + v.y + v.z + v.w;
        float sq = v.x * v.x + v.y * v.y + v.z * v.z + v.w * v.w;
#pragma unroll
        for (int off = 32; off > 0; off >>= 1) {
            s  += __shfl_xor(s, off, 64);
            sq += __shfl_xor(sq, off, 64);
        }
        float mean = s * (1.0f / 256.0f);
        float var  = sq * (1.0f / 256.0f) - mean * mean;
        float r = rsqrtf(var + 1e-5f);
        float4 wv = *(const float4*)(ln1_w + lane * 4);
        float4 bv = *(const float4*)(ln1_b + lane * 4);
        ushortT o[4] = {f2bf((v.x - mean) * r * wv.x + bv.x),
                        f2bf((v.y - mean) * r * wv.y + bv.y),
                        f2bf((v.z - mean) * r * wv.z + bv.z),
                        f2bf((v.w - mean) * r * wv.w + bv.w)};
        *(uint2*)(xn + (size_t)t * 256 + lane * 4) = *(uint2*)o;
    }
}

// ---------------- LayerNorm v2: one wave per token -------------------------
__global__ __launch_bounds__(256) void ln_v2(const float* __restrict__ x,
                                             const float* __restrict__ w,
                                             const float* __restrict__ b,
                                             ushortT* __restrict__ y) {
    int wave = threadIdx.x >> 6, lane = threadIdx.x & 63;
    int t = blockIdx.x * 4 + wave;
    float4 v = *(const float4*)(x + (size_t)t * 256 + lane * 4);
    float s = v.x + v.y + v.z + v.w;
    float sq = v.x * v.x + v.y * v.y + v.z * v.z + v.w * v.w;
#pragma unroll
    for (int off = 32; off > 0; off >>= 1) {
        s  += __shfl_xor(s, off, 64);
        sq += __shfl_xor(sq, off, 64);
    }
    float mean = s * (1.0f / 256.0f);
    float var  = sq * (1.0f / 256.0f) - mean * mean;
    float r = rsqrtf(var + 1e-5f);
    float4 wv = *(const float4*)(w + lane * 4);
    float4 bv = *(const float4*)(b + lane * 4);
    ushortT o[4] = {f2bf((v.x - mean) * r * wv.x + bv.x),
                    f2bf((v.y - mean) * r * wv.y + bv.y),
                    f2bf((v.z - mean) * r * wv.z + bv.z),
                    f2bf((v.w - mean) * r * wv.w + bv.w)};
    *(uint2*)(y + (size_t)t * 256 + lane * 4) = *(uint2*)o;
}

// ---------------- bf16 MFMA GEMM (round-5 structure): C = A @ Bw^T + bias ----
// 64x64 block tile, BK=64, 256 threads = 4 waves (2x2), each wave 32x32.
// LDS: [row][128B], XOR-swizzled chunks: chunk c of row r at pos c^(r&7).
// EPI: 0 = qkv split-heads bf16 (q pre-scaled), 2 = bias + exact GELU -> bf16
template <int EPI>
__global__ __launch_bounds__(256) void gemm_bf16_v2(const ushortT* __restrict__ A,
                                                    const ushortT* __restrict__ Bw,
                                                    const float* __restrict__ bias,
                                                    void* __restrict__ out0,
                                                    ushortT* __restrict__ kb,
                                                    ushortT* __restrict__ vb,
                                                    int N, int K) {
    __shared__ ushortT As[64 * 64];  // 8KB
    __shared__ ushortT Bs[64 * 64];
    const int tid  = threadIdx.x;
    const int wave = tid >> 6, lane = tid & 63;
    const int wm = wave >> 1, wn = wave & 1;
    const int ln16 = lane & 15, kg = lane >> 4;
    const int m0 = blockIdx.y * 64, n0 = blockIdx.x * 64;
    const int g8 = (((lane & 7) ^ (lane >> 3)) * 8);  // swizzled global chunk
    const int srow = wave * 16 + (lane >> 3);         // +8 for pass 1

    const floatx4 fzero = {0.f, 0.f, 0.f, 0.f};
    floatx4 acc[2][2];
#pragma unroll
    for (int i = 0; i < 2; ++i)
#pragma unroll
        for (int j = 0; j < 2; ++j) acc[i][j] = fzero;

    for (int kt = 0; kt < K; kt += 64) {
#pragma unroll
        for (int p = 0; p < 2; ++p) {
            int row = srow + p * 8;
            GLOAD_LDS16(A  + (size_t)(m0 + row) * K + kt + g8, As + wave * 1024 + p * 512);
            GLOAD_LDS16(Bw + (size_t)(n0 + row) * K + kt + g8, Bs + wave * 1024 + p * 512);
        }
        __syncthreads();
#pragma unroll
        for (int s = 0; s < 2; ++s) {
            short8 a[2], b[2];
#pragma unroll
            for (int i = 0; i < 2; ++i) {
                int ra = wm * 32 + i * 16 + ln16;
                a[i] = *(const short8*)(As + ra * 64 + (((s * 4 + kg) ^ (ra & 7)) * 8));
            }
#pragma unroll
            for (int j = 0; j < 2; ++j) {
                int rb = wn * 32 + j * 16 + ln16;
                b[j] = *(const short8*)(Bs + rb * 64 + (((s * 4 + kg) ^ (rb & 7)) * 8));
            }
#pragma unroll
            for (int i = 0; i < 2; ++i)
#pragma unroll
                for (int j = 0; j < 2; ++j)
                    acc[i][j] = __builtin_amdgcn_mfma_f32_16x16x32_bf16(a[i], b[j], acc[i][j], 0, 0, 0);
        }
        __syncthreads();
    }

    // epilogue: C/D map col=ln16, row=kg*4+reg
#pragma unroll
    for (int j = 0; j < 2; ++j) {
        int col = n0 + wn * 32 + j * 16 + ln16;
        float bsv = bias[col];
        if (EPI == 0) {
            // qkv: col in [0,768): part|head|dim -> head-major [b*8+h][4096][32] bf16
            int part = col >> 8, h = (col >> 5) & 7, d = col & 31;
            ushortT* dst = part == 0 ? (ushortT*)out0 : (part == 1 ? kb : vb);
            float scl = part == 0 ? 0.17677669529663687f : 1.0f;
#pragma unroll
            for (int i = 0; i < 2; ++i)
#pragma unroll
                for (int r = 0; r < 4; ++r) {
                    int row = m0 + wm * 32 + i * 16 + kg * 4 + r;
                    int bI = row >> 12, tin = row & 4095;
                    dst[((size_t)(bI * 8 + h) * 4096 + tin) * 32 + d] =
                        f2bf((acc[i][j][r] + bsv) * scl);
                }
        } else {
#pragma unroll
            for (int i = 0; i < 2; ++i)
#pragma unroll
                for (int r = 0; r < 4; ++r) {
                    int row = m0 + wm * 32 + i * 16 + kg * 4 + r;
                    float v = acc[i][j][r] + bsv;
                    v = 0.5f * v * (1.0f + erff(v * 0.70710678118654752f));
                    ((ushortT*)out0)[(size_t)row * N + col] = f2bf(v);
                }
        }
    }
}

// ---------------- skinny GEMM (N=256): 32x64 tile, BK=64, res + bias -> fp32 -
// 256 threads = 4 waves (2x2), wave tile 16m x 32n (1x2 acc). 12KB LDS.
__global__ __launch_bounds__(256) void gemm_skinny(const ushortT* __restrict__ A,
                                                   const ushortT* __restrict__ Bw,
                                                   const float* __restrict__ bias,
                                                   const float* __restrict__ res,
                                                   float* __restrict__ out,
                                                   int K) {
    __shared__ ushortT As[32 * 64];  // 4KB
    __shared__ ushortT Bs[64 * 64];  // 8KB
    const int tid  = threadIdx.x;
    const int wave = tid >> 6, lane = tid & 63;
    const int wm = wave >> 1, wn = wave & 1;
    const int ln16 = lane & 15, kg = lane >> 4;
    const int m0 = blockIdx.y * 32, n0 = blockIdx.x * 64;
    const int srow = tid >> 3;            // 0..31
    const int spos = tid & 7;
    const int sgc  = spos ^ (srow & 7);   // swizzled global chunk
    const int brow = wave * 16 + (lane >> 3);  // B staging row (+8 for pass 1)
    const int bg8  = (((lane & 7) ^ (lane >> 3)) * 8);

    const floatx4 fzero = {0.f, 0.f, 0.f, 0.f};
    floatx4 acc[2] = {fzero, fzero};

    for (int kt = 0; kt < K; kt += 64) {
        GLOAD_LDS16(A + (size_t)(m0 + srow) * K + kt + sgc * 8, As + (tid - lane) * 8);
#pragma unroll
        for (int p = 0; p < 2; ++p) {
            int row = brow + p * 8;
            GLOAD_LDS16(Bw + (size_t)(n0 + row) * K + kt + bg8, Bs + wave * 1024 + p * 512);
        }
        __syncthreads();
#pragma unroll
        for (int s = 0; s < 2; ++s) {
            int c = s * 4 + kg;
            int ra = wm * 16 + ln16;
            short8 a = *(const short8*)(As + ra * 64 + ((c ^ (ra & 7)) * 8));
            short8 b[2];
#pragma unroll
            for (int j = 0; j < 2; ++j) {
                int rb = wn * 32 + j * 16 + ln16;
                b[j] = *(const short8*)(Bs + rb * 64 + ((c ^ (rb & 7)) * 8));
            }
            acc[0] = __builtin_amdgcn_mfma_f32_16x16x32_bf16(a, b[0], acc[0], 0, 0, 0);
            acc[1] = __builtin_amdgcn_mfma_f32_16x16x32_bf16(a, b[1], acc[1], 0, 0, 0);
        }
        __syncthreads();
    }

#pragma unroll
    for (int j = 0; j < 2; ++j) {
        int col = n0 + wn * 32 + j * 16 + ln16;
        float bsv = bias[col];
#pragma unroll
        for (int r = 0; r < 4; ++r) {
            int row = m0 + wm * 16 + kg * 4 + r;
            out[(size_t)row * 256 + col] = acc[j][r] + bsv + res[(size_t)row * 256 + col];
        }
    }
}

// ---------------- Neighborhood attention v3 ----------------------------------
__global__ __launch_bounds__(256) void natten_v3(const ushortT* __restrict__ qb,
                                                 const ushortT* __restrict__ kb,
                                                 const ushortT* __restrict__ vb,
                                                 ushortT* __restrict__ attn_out) {
    __shared__ ushortT KVs[2 * 196 * 40];  // K rows then V rows, stride 40 (80B)
    __shared__ float Ps[64][52];
    ushortT* Ks = KVs;
    ushortT* Vs = KVs + 196 * 40;
    const int tid = threadIdx.x, bid = blockIdx.x;
    const int tile = bid & 63, h = (bid >> 6) & 7, b = bid >> 9;
    const int ti = tile >> 3, tj = tile & 7;
    const int r0 = min(max(ti * 8 - 3, 0), Hdim - 14);
    const int c0 = min(max(tj * 8 - 3, 0), Wdim - 14);
    const size_t base = (size_t)(b * 8 + h) * 4096 * 32;

    for (int idx = tid; idx < 1568; idx += 256) {
        int t = idx;
        const ushortT* src = kb;
        ushortT* dst = Ks;
        if (t >= 784) { t -= 784; src = vb; dst = Vs; }
        int pos = t >> 2, ch = t & 3;
        int dr = pos / 14, dc = pos - dr * 14;
        int tok = (r0 + dr) * 64 + (c0 + dc);
        *(uint4*)(dst + pos * 40 + ch * 8) = *(const uint4*)(src + base + (size_t)tok * 32 + ch * 8);
    }

    const int tl = tid >> 2, s = tid & 3;
    const int i = ti * 8 + (tl >> 3), j = tj * 8 + (tl & 7);
    const int si = min(max(i - 3, 0), Hdim - 7), sj = min(max(j - 3, 0), Wdim - 7);
    const int lbase = (si - r0) * 14 + (sj - c0);
    const int tin = i * 64 + j;

    float q[32];
    {
        const ushortT* qp = qb + base + (size_t)tin * 32;
#pragma unroll
        for (int c4 = 0; c4 < 4; ++c4) {
            uint4 u = *(const uint4*)(qp + c4 * 8);
            unsigned uu[4] = {u.x, u.y, u.z, u.w};
#pragma unroll
            for (int e = 0; e < 4; ++e) {
                union { unsigned v; float f; } lo, hi;
                lo.v = uu[e] << 16; hi.v = uu[e] & 0xffff0000u;
                q[c4 * 8 + e * 2] = lo.f; q[c4 * 8 + e * 2 + 1] = hi.f;
            }
        }
    }
    __syncthreads();

    float sc[13];
#pragma unroll
    for (int cI = 0; cI < 13; ++cI) {
        int n = s + cI * 4;
        if (n < 49) {
            int di = n / 7, dj = n - di * 7;
            const ushortT* kr = Ks + (lbase + di * 14 + dj) * 40;
            float a = 0.f;
#pragma unroll
            for (int c4 = 0; c4 < 4; ++c4) {
                uint4 u = *(const uint4*)(kr + c4 * 8);
                unsigned uu[4] = {u.x, u.y, u.z, u.w};
#pragma unroll
                for (int e = 0; e < 4; ++e) {
                    union { unsigned v; float f; } lo, hi;
                    lo.v = uu[e] << 16; hi.v = uu[e] & 0xffff0000u;
                    a += q[c4 * 8 + e * 2] * lo.f + q[c4 * 8 + e * 2 + 1] * hi.f;
                }
            }
            sc[cI] = a;
        }
    }
    float m = -1e30f;
#pragma unroll
    for (int cI = 0; cI < 13; ++cI) if (s + cI * 4 < 49) m = fmaxf(m, sc[cI]);
    m = fmaxf(m, __shfl_xor(m, 1, 64));
    m = fmaxf(m, __shfl_xor(m, 2, 64));
    float tot = 0.f;
#pragma unroll
    for (int cI = 0; cI < 13; ++cI) if (s + cI * 4 < 49) { sc[cI] = __expf(sc[cI] - m); tot += sc[cI]; }
    tot += __shfl_xor(tot, 1, 64);
    tot += __shfl_xor(tot, 2, 64);
    float inv = 1.0f / tot;
#pragma unroll
    for (int cI = 0; cI < 13; ++cI) if (s + cI * 4 < 49) Ps[tl][s + cI * 4] = sc[cI] * inv;
    __syncthreads();

    float o[8] = {0.f, 0.f, 0.f, 0.f, 0.f, 0.f, 0.f, 0.f};
#pragma unroll
    for (int n = 0; n < 49; ++n) {
        int di = n / 7, dj = n - di * 7;
        float p = Ps[tl][n];
        const ushortT* vr = Vs + (lbase + di * 14 + dj) * 40 + s * 8;
        uint4 u = *(const uint4*)vr;
        unsigned uu[4] = {u.x, u.y, u.z, u.w};
#pragma unroll
        for (int e = 0; e < 4; ++e) {
            union { unsigned v; float f; } lo, hi;
            lo.v = uu[e] << 16; hi.v = uu[e] & 0xffff0000u;
            o[e * 2]     += p * lo.f;
            o[e * 2 + 1] += p * hi.f;
        }
    }
    unsigned up[4];
#pragma unroll
    for (int d = 0; d < 4; ++d)
        up[d] = (unsigned)f2bf(o[2 * d]) | ((unsigned)f2bf(o[2 * d + 1]) << 16);
    size_t tq = (size_t)(b * 4096 + tin);
    *(uint4*)(attn_out + tq * 256 + h * 32 + s * 8) = make_uint4(up[0], up[1], up[2], up[3]);
}

extern "C" void kernel_launch(void* const* d_in, const int* in_sizes, int n_in,
                              void* d_out, int out_size, void* d_ws, size_t ws_size,
                              hipStream_t stream) {
    const float* x      = (const float*)d_in[0];
    const float* ln1_w  = (const float*)d_in[1];
    const float* ln1_b  = (const float*)d_in[2];
    const float* qkv_w  = (const float*)d_in[3];
    const float* qkv_b  = (const float*)d_in[4];
    const float* proj_w = (const float*)d_in[5];
    const float* proj_b = (const float*)d_in[6];
    const float* ln2_w  = (const float*)d_in[7];
    const float* ln2_b  = (const float*)d_in[8];
    const float* fc1_w  = (const float*)d_in[9];
    const float* fc1_b  = (const float*)d_in[10];
    const float* fc2_w  = (const float*)d_in[11];
    const float* fc2_b  = (const float*)d_in[12];
    float* out = (float*)d_out;

    char* ws = (char*)d_ws;
    size_t off = 0;
    ushortT* wqkv = (ushortT*)(ws + off); off += (size_t)196608 * 2;
    ushortT* wproj= (ushortT*)(ws + off); off += (size_t)65536 * 2;
    ushortT* wfc1 = (ushortT*)(ws + off); off += (size_t)262144 * 2;
    ushortT* wfc2 = (ushortT*)(ws + off); off += (size_t)262144 * 2;
    ushortT* xn   = (ushortT*)(ws + off); off += (size_t)NTOK * 256 * 2;
    ushortT* qbuf = (ushortT*)(ws + off); off += (size_t)NTOK * 256 * 2;
    ushortT* kbuf = (ushortT*)(ws + off); off += (size_t)NTOK * 256 * 2;
    ushortT* vbuf = (ushortT*)(ws + off); off += (size_t)NTOK * 256 * 2;
    ushortT* attn = (ushortT*)(ws + off); off += (size_t)NTOK * 256 * 2;
    float*   x2   = (float*)  (ws + off); off += (size_t)NTOK * 256 * 4;
    ushortT* hb   = (ushortT*)(ws + off); off += (size_t)NTOK * 256 * 2;
    ushortT* h1   = (ushortT*)(ws + off); off += (size_t)NTOK * 1024 * 2;

    dim3 blk(256);
    prep_kernel<<<2816, blk, 0, stream>>>(qkv_w, proj_w, fc1_w, fc2_w,
                                          wqkv, wproj, wfc1, wfc2,
                                          x, ln1_w, ln1_b, xn);
    gemm_bf16_v2<0><<<dim3(12, 128), blk, 0, stream>>>(xn, wqkv, qkv_b,
                                                       qbuf, kbuf, vbuf, 768, 256);
    natten_v3<<<1024, blk, 0, stream>>>(qbuf, kbuf, vbuf, attn);
    gemm_skinny<<<dim3(4, 256), blk, 0, stream>>>(attn, wproj, proj_b, x, x2, 256);
    ln_v2<<<2048, blk, 0, stream>>>(x2, ln2_w, ln2_b, hb);
    gemm_bf16_v2<2><<<dim3(16, 128), blk, 0, stream>>>(hb, wfc1, fc1_b,
                                                       h1, nullptr, nullptr, 1024, 256);
    gemm_skinny<<<dim3(4, 256), blk, 0, stream>>>(h1, wfc2, fc2_b, x2, out, 1024);
}